// Round 5
// baseline (209.437 us; speedup 1.0000x reference)
//
#include <hip/hip_runtime.h>

// LiteralE: out[b] = f(index[b]); f(n) = Z*H + (1-Z)*e[n],
// Z = sigmoid(W_ze[n]·e[n] + W_zl[n]·l[n] + b), H = tanh(W_he[n]·e[n] + W_hl[n]·l[n]).
//
// out depends only on n -> compute f once per unique entity, then gather.
// Round 5: dense worklist (atomic append) + 4 blocks per entity (32 rows /
// 48KB each) to shrink the scheduling tail; memset replaces the zero kernel.

constexpr int H_DIM = 128;
constexpr int N_D   = 64;
constexpr int N_ENT = 10000;
constexpr int ROWS_PER_BLK = 32;            // 4 blocks per entity

__global__ void k_mark(const int* __restrict__ index, int* __restrict__ used,
                       int* __restrict__ count, int* __restrict__ list, int B) {
    const int b = blockIdx.x * blockDim.x + threadIdx.x;
    if (b < B) {
        const int n = index[b];
        if (atomicExch(&used[n], 1) == 0) {
            const int p = atomicAdd(count, 1);
            list[p] = n;
        }
    }
}

// grid = 4 * N_ENT blocks; block bid handles row-quarter (bid&3) of
// entity list[bid>>2]. Dense early-exit for bid>>2 >= count.
__global__ __launch_bounds__(256) void k_compute_unique(
    const float* __restrict__ e,
    const float* __restrict__ l,
    const float* __restrict__ W_ze,
    const float* __restrict__ W_zl,
    const float* __restrict__ W_he,
    const float* __restrict__ W_hl,
    const float* __restrict__ bias,
    const int*  __restrict__ count,
    const int*  __restrict__ list,
    float* __restrict__ uout)
{
    const int bid = blockIdx.x;
    const int ei  = bid >> 2;
    if (ei >= *count) return;
    const int q = bid & 3;                 // row quarter 0..3
    const long long n = (long long)list[ei];

    const int tid  = threadIdx.x;
    const int wave = tid >> 6;
    const int lane = tid & 63;
    const int g    = lane >> 4;            // row within wave's 4-row group
    const int j    = lane & 15;            // column-chunk lane

    __shared__ float az_s[ROWS_PER_BLK];
    __shared__ float ah_s[ROWS_PER_BLK];

    const float4* ep = reinterpret_cast<const float4*>(e + n * H_DIM);
    const float4 xe0 = ep[j];
    const float4 xe1 = ep[j + 16];
    const float4 xl  = reinterpret_cast<const float4*>(l + n * N_D)[j];

    const float4* wze = reinterpret_cast<const float4*>(W_ze + n * (size_t)(H_DIM * H_DIM));
    const float4* whe = reinterpret_cast<const float4*>(W_he + n * (size_t)(H_DIM * H_DIM));
    const float4* wzl = reinterpret_cast<const float4*>(W_zl + n * (size_t)(H_DIM * N_D));
    const float4* whl = reinterpret_cast<const float4*>(W_hl + n * (size_t)(H_DIM * N_D));

    #pragma unroll
    for (int pass = 0; pass < 2; ++pass) {
        const int rl = pass * 16 + wave * 4 + g;   // 0..31 local row
        const int r  = q * ROWS_PER_BLK + rl;      // global row 0..127

        const float4 a0 = wze[r * 32 + j];
        const float4 a1 = wze[r * 32 + j + 16];
        const float4 b0 = whe[r * 32 + j];
        const float4 b1 = whe[r * 32 + j + 16];
        const float4 c0 = wzl[r * 16 + j];
        const float4 d0 = whl[r * 16 + j];

        float pz = fmaf(a0.x, xe0.x, fmaf(a0.y, xe0.y, fmaf(a0.z, xe0.z, a0.w * xe0.w)));
        pz = fmaf(a1.x, xe1.x, fmaf(a1.y, xe1.y, fmaf(a1.z, xe1.z, fmaf(a1.w, xe1.w, pz))));
        pz = fmaf(c0.x, xl.x,  fmaf(c0.y, xl.y,  fmaf(c0.z, xl.z,  fmaf(c0.w, xl.w,  pz))));

        float ph = fmaf(b0.x, xe0.x, fmaf(b0.y, xe0.y, fmaf(b0.z, xe0.z, b0.w * xe0.w)));
        ph = fmaf(b1.x, xe1.x, fmaf(b1.y, xe1.y, fmaf(b1.z, xe1.z, fmaf(b1.w, xe1.w, ph))));
        ph = fmaf(d0.x, xl.x,  fmaf(d0.y, xl.y,  fmaf(d0.z, xl.z,  fmaf(d0.w, xl.w,  ph))));

        #pragma unroll
        for (int m = 1; m <= 8; m <<= 1) {
            pz += __shfl_xor(pz, m, 64);
            ph += __shfl_xor(ph, m, 64);
        }
        if (j == 0) { az_s[rl] = pz; ah_s[rl] = ph; }
    }
    __syncthreads();

    if (tid < ROWS_PER_BLK) {
        const int r = q * ROWS_PER_BLK + tid;
        const float zg = 1.0f / (1.0f + __expf(-(az_s[tid] + bias[r])));
        const float hc = tanhf(ah_s[tid]);
        const float ei_v = e[n * H_DIM + r];
        uout[n * H_DIM + r] = zg * hc + (1.0f - zg) * ei_v;
    }
}

__global__ void k_gather(const int* __restrict__ index,
                         const float* __restrict__ uout,
                         float* __restrict__ out, int B)
{
    const int i = blockIdx.x * blockDim.x + threadIdx.x;   // one float4 each
    if (i < B * (H_DIM / 4)) {
        const int b = i >> 5;
        const int c = i & 31;
        const long long n = (long long)index[b];
        reinterpret_cast<float4*>(out)[(size_t)b * 32 + c] =
            reinterpret_cast<const float4*>(uout)[n * 32 + c];
    }
}

// ---- Fallback (monolithic) if ws_size is too small ----
constexpr int ELEMS = 4;
__global__ __launch_bounds__(256) void literal_e_fused(
    const float* __restrict__ e, const float* __restrict__ l,
    const float* __restrict__ W_ze, const float* __restrict__ W_zl,
    const float* __restrict__ W_he, const float* __restrict__ W_hl,
    const float* __restrict__ bias, const int* __restrict__ index,
    float* __restrict__ out)
{
    const int tid  = threadIdx.x;
    const int wave = tid >> 6;
    const int lane = tid & 63;
    const int g    = lane >> 4;
    const int j    = lane & 15;

    __shared__ float se[H_DIM];
    __shared__ float az_s[H_DIM];
    __shared__ float ah_s[H_DIM];

    const long long base = (long long)blockIdx.x * ELEMS;
    for (int it = 0; it < ELEMS; ++it) {
        const long long n  = (long long)index[base + it];
        const long long bi = base + it;
        const float4* ep = reinterpret_cast<const float4*>(e + n * H_DIM);
        const float4 xe0 = ep[j];
        const float4 xe1 = ep[j + 16];
        const float4 xl  = reinterpret_cast<const float4*>(l + n * N_D)[j];
        if (tid < H_DIM) se[tid] = e[n * H_DIM + tid];

        const float4* wze = reinterpret_cast<const float4*>(W_ze + n * (size_t)(H_DIM * H_DIM));
        const float4* whe = reinterpret_cast<const float4*>(W_he + n * (size_t)(H_DIM * H_DIM));
        const float4* wzl = reinterpret_cast<const float4*>(W_zl + n * (size_t)(H_DIM * N_D));
        const float4* whl = reinterpret_cast<const float4*>(W_hl + n * (size_t)(H_DIM * N_D));

        #pragma unroll 4
        for (int pass = 0; pass < 8; ++pass) {
            const int r = pass * 16 + wave * 4 + g;
            const float4 a0 = wze[r * 32 + j];
            const float4 a1 = wze[r * 32 + j + 16];
            const float4 b0 = whe[r * 32 + j];
            const float4 b1 = whe[r * 32 + j + 16];
            const float4 c0 = wzl[r * 16 + j];
            const float4 d0 = whl[r * 16 + j];
            float pz = fmaf(a0.x, xe0.x, fmaf(a0.y, xe0.y, fmaf(a0.z, xe0.z, a0.w * xe0.w)));
            pz = fmaf(a1.x, xe1.x, fmaf(a1.y, xe1.y, fmaf(a1.z, xe1.z, fmaf(a1.w, xe1.w, pz))));
            pz = fmaf(c0.x, xl.x,  fmaf(c0.y, xl.y,  fmaf(c0.z, xl.z,  fmaf(c0.w, xl.w,  pz))));
            float ph = fmaf(b0.x, xe0.x, fmaf(b0.y, xe0.y, fmaf(b0.z, xe0.z, b0.w * xe0.w)));
            ph = fmaf(b1.x, xe1.x, fmaf(b1.y, xe1.y, fmaf(b1.z, xe1.z, fmaf(b1.w, xe1.w, ph))));
            ph = fmaf(d0.x, xl.x,  fmaf(d0.y, xl.y,  fmaf(d0.z, xl.z,  fmaf(d0.w, xl.w,  ph))));
            #pragma unroll
            for (int m = 1; m <= 8; m <<= 1) {
                pz += __shfl_xor(pz, m, 64);
                ph += __shfl_xor(ph, m, 64);
            }
            if (j == 0) { az_s[r] = pz; ah_s[r] = ph; }
        }
        __syncthreads();
        if (tid < H_DIM) {
            const float zg = 1.0f / (1.0f + __expf(-(az_s[tid] + bias[tid])));
            const float hc = tanhf(ah_s[tid]);
            out[bi * H_DIM + tid] = zg * hc + (1.0f - zg) * se[tid];
        }
        __syncthreads();
    }
}

extern "C" void kernel_launch(void* const* d_in, const int* in_sizes, int n_in,
                              void* d_out, int out_size, void* d_ws, size_t ws_size,
                              hipStream_t stream) {
    const float* e    = (const float*)d_in[0];
    const float* l    = (const float*)d_in[1];
    const float* W_ze = (const float*)d_in[2];
    const float* W_zl = (const float*)d_in[3];
    const float* W_he = (const float*)d_in[4];
    const float* W_hl = (const float*)d_in[5];
    const float* bias = (const float*)d_in[6];
    const int*   idx  = (const int*)d_in[7];
    float* out = (float*)d_out;

    const int B = in_sizes[7];   // 8192

    const size_t uout_bytes = (size_t)N_ENT * H_DIM * sizeof(float);   // 5.12 MB
    const size_t need = uout_bytes + (size_t)(2 * N_ENT + 1) * sizeof(int);

    if (ws_size >= need) {
        float* uout  = (float*)d_ws;
        int*   used  = (int*)((char*)d_ws + uout_bytes);   // [N_ENT]
        int*   count = used + N_ENT;                        // [1]
        int*   list  = count + 1;                           // [N_ENT]

        // zero used+count in one capture-legal memset
        hipMemsetAsync(used, 0, (size_t)(N_ENT + 1) * sizeof(int), stream);
        k_mark<<<dim3((B + 255) / 256), dim3(256), 0, stream>>>(idx, used, count, list, B);
        k_compute_unique<<<dim3(4 * N_ENT), dim3(256), 0, stream>>>(
            e, l, W_ze, W_zl, W_he, W_hl, bias, count, list, uout);
        k_gather<<<dim3((B * (H_DIM / 4) + 255) / 256), dim3(256), 0, stream>>>(
            idx, uout, out, B);
    } else {
        literal_e_fused<<<dim3(B / ELEMS), dim3(256), 0, stream>>>(
            e, l, W_ze, W_zl, W_he, W_hl, bias, idx, out);
    }
}